// Round 10
// baseline (744.840 us; speedup 1.0000x reference)
//
#include <hip/hip_runtime.h>
#include <hip/hip_bf16.h>

typedef unsigned int u32;
typedef unsigned char u8;
typedef __attribute__((ext_vector_type(2))) float f2;

#define B_ 256
#define T_ 512
#define E_ 100
#define H_ 64
#define K_ 17
#define V_ 8000

// ---- ws layout (bytes) ----
#define WS_G     0            // 2 * 8000 * 256 * 4 = 16,384,000
#define WS_H     16384000     // 2 * 256 * 512 * 64 * 4 = 67,108,864
#define WS_EMIT  83492864     // 131072 * 17 * 4 = 8,912,896
#define WS_BP    92405760     // 256 * 512 * 32 = 4,194,304
#define WS_LAST  96600064     // 256 * 4

#define PINF4(v) asm volatile("" : "+v"((v).x), "+v"((v).y), "+v"((v).z), "+v"((v).w))
#define PINF2(v) asm volatile("" : "+v"(v))
#define FMA2(a, b, c) __builtin_elementwise_fma((a), (b), (c))

// quad_perm DPP: xor1 = [1,0,3,2] = 0xB1, xor2 = [2,3,0,1] = 0x4E
__device__ __forceinline__ float qp_xor1(float v) {
  int r = __builtin_amdgcn_update_dpp(0, __builtin_bit_cast(int, v), 0xB1, 0xF, 0xF, true);
  return __builtin_bit_cast(float, r);
}
__device__ __forceinline__ float qp_xor2(float v) {
  int r = __builtin_amdgcn_update_dpp(0, __builtin_bit_cast(int, v), 0x4E, 0xF, 0xF, true);
  return __builtin_bit_cast(float, r);
}
__device__ __forceinline__ float rdl(float v, int lane) {
  return __builtin_bit_cast(float, __builtin_amdgcn_readlane(__builtin_bit_cast(int, v), lane));
}

// ============ K1: G[v][u*4+g] = emb[v] @ Wih[g*64+u].T + bih + bhh ============
__global__ __launch_bounds__(256)
__attribute__((amdgpu_waves_per_eu(2, 2)))
void k1_build_G(
    const float* __restrict__ emb,
    const float* __restrict__ Wih_f,
    const float* __restrict__ bih_f,
    const float* __restrict__ bhh_f,
    const float* __restrict__ Wih_b,
    const float* __restrict__ bih_b,
    const float* __restrict__ bhh_b,
    float* __restrict__ G)
{
  __shared__ float xl[32 * E_];
  int v0 = blockIdx.x * 32;
  int dir = blockIdx.y;
  int tid = threadIdx.x;
  const float* Wih = dir ? Wih_b : Wih_f;
  const float* bih = dir ? bih_b : bih_f;
  const float* bhh = dir ? bhh_b : bhh_f;

  for (int i = tid; i < 32 * E_; i += 256) xl[i] = emb[v0 * E_ + i];

  int u = tid >> 2, g = tid & 3;
  int row = (g << 6) + u;
  const float* wr = Wih + row * E_;   // 400B rows, 16B aligned
#define LDA(name, q) float4 name = *reinterpret_cast<const float4*>(wr + 4 * (q)); PINF4(name)
  LDA(A0,0);  LDA(A1,1);  LDA(A2,2);  LDA(A3,3);  LDA(A4,4);
  LDA(A5,5);  LDA(A6,6);  LDA(A7,7);  LDA(A8,8);  LDA(A9,9);
  LDA(A10,10);LDA(A11,11);LDA(A12,12);LDA(A13,13);LDA(A14,14);
  LDA(A15,15);LDA(A16,16);LDA(A17,17);LDA(A18,18);LDA(A19,19);
  LDA(A20,20);LDA(A21,21);LDA(A22,22);LDA(A23,23);LDA(A24,24);
#undef LDA
  float bias = __fadd_rn(bih[row], bhh[row]);
  __syncthreads();

  float* Gd = G + (size_t)dir * V_ * 256;
  for (int vi = 0; vi < 32; ++vi) {
    const float* xp = &xl[vi * E_];
    float a0 = bias, a1 = 0.f, a2 = 0.f, a3 = 0.f;
#define K1F(Aq, q) { float4 x4 = *reinterpret_cast<const float4*>(xp + 4 * (q)); \
    a0 = fmaf(Aq.x, x4.x, a0); a1 = fmaf(Aq.y, x4.y, a1); \
    a2 = fmaf(Aq.z, x4.z, a2); a3 = fmaf(Aq.w, x4.w, a3); }
    K1F(A0,0)  K1F(A1,1)  K1F(A2,2)  K1F(A3,3)  K1F(A4,4)
    K1F(A5,5)  K1F(A6,6)  K1F(A7,7)  K1F(A8,8)  K1F(A9,9)
    K1F(A10,10)K1F(A11,11)K1F(A12,12)K1F(A13,13)K1F(A14,14)
    K1F(A15,15)K1F(A16,16)K1F(A17,17)K1F(A18,18)K1F(A19,19)
    K1F(A20,20)K1F(A21,21)K1F(A22,22)K1F(A23,23)K1F(A24,24)
#undef K1F
    Gd[(v0 + vi) * 256 + tid] = (a0 + a1) + (a2 + a3);
  }
}

// ============ K2: BiLSTM recurrence. 1 block = (b, dir), 4 waves ============
// Round-10: GDOT via v_pk_fma_f32 (float2 ext-vector fma -> VOP3P packed fp32,
// 2 MAC/inst; per-component rounding identical to fmaf). Everything else
// carried from r9 (weights pinned resident, LDS tokens, saddr G loads).
__global__ __launch_bounds__(256)
__attribute__((amdgpu_waves_per_eu(2, 2)))
void k2_lstm(
    const int* __restrict__ data,
    const float* __restrict__ G,
    const float* __restrict__ Whh_f,
    const float* __restrict__ Whh_b,
    float* __restrict__ hout)
{
  __shared__ __align__(16) float hls[2][64];
  __shared__ int tok_lds[T_ + 8];
  int bid = blockIdx.x;
  int b = bid & 255;
  int dir = bid >> 8;
  int tid = threadIdx.x;
  int w = tid >> 6, l = tid & 63;
  int ul = l >> 2;           // 0..15
  int kq = l & 3;            // K-quarter
  int u = (w << 4) + ul;     // 0..63
  const float* Whh = dir ? Whh_b : Whh_f;
  // f2 view: gate g starts at g*4096 floats = g*2048 f2; our slice at u*64+kq*16
  const f2* wb2 = reinterpret_cast<const f2*>(Whh + u * 64 + (kq << 4));

#define LDW(pre, g) \
  f2 pre##0 = wb2[(g)*2048+0]; f2 pre##1 = wb2[(g)*2048+1]; \
  f2 pre##2 = wb2[(g)*2048+2]; f2 pre##3 = wb2[(g)*2048+3]; \
  f2 pre##4 = wb2[(g)*2048+4]; f2 pre##5 = wb2[(g)*2048+5]; \
  f2 pre##6 = wb2[(g)*2048+6]; f2 pre##7 = wb2[(g)*2048+7]; \
  PINF2(pre##0); PINF2(pre##1); PINF2(pre##2); PINF2(pre##3); \
  PINF2(pre##4); PINF2(pre##5); PINF2(pre##6); PINF2(pre##7)
  LDW(Wa, 0); LDW(Wb, 1); LDW(Wc, 2); LDW(Wd, 3);
#undef LDW

  // stage tokens in step order (dir-reversed for bwd); pad tail with 0
  const int* tokp = data + b * T_;
  for (int i = tid; i < T_; i += 256)
    tok_lds[i] = tokp[dir ? (T_ - 1 - i) : i];
  if (tid < 8) tok_lds[T_ + tid] = 0;
  if (tid < 64) hls[0][tid] = 0.0f;
  __syncthreads();

  float c = 0.0f;
  const float* Gd = G + (size_t)dir * V_ * 256;
  float* hob = hout + ((size_t)(dir * B_ + b)) * T_ * H_;
  float* hop = hob + (dir ? (T_ - 1) * H_ : 0) + u;
  int hstep = dir ? -H_ : H_;
  const float L2E = 1.4426950408889634f;

  // 4-deep G ring (tokens block-uniform -> saddr loads)
  float4 gq0, gq1, gq2, gq3;
  {
    int t0 = __builtin_amdgcn_readfirstlane(tok_lds[0]);
    int t1 = __builtin_amdgcn_readfirstlane(tok_lds[1]);
    int t2 = __builtin_amdgcn_readfirstlane(tok_lds[2]);
    int t3 = __builtin_amdgcn_readfirstlane(tok_lds[3]);
    gq0 = *reinterpret_cast<const float4*>(Gd + ((size_t)t0 << 8) + (u << 2));
    gq1 = *reinterpret_cast<const float4*>(Gd + ((size_t)t1 << 8) + (u << 2));
    gq2 = *reinterpret_cast<const float4*>(Gd + ((size_t)t2 << 8) + (u << 2));
    gq3 = *reinterpret_cast<const float4*>(Gd + ((size_t)t3 << 8) + (u << 2));
  }
  int tk_next = tok_lds[4];

  int cur = 0;
#pragma unroll 2
  for (int s = 0; s < T_; ++s) {
    int tokn = __builtin_amdgcn_readfirstlane(tk_next);
    float4 gq4 = *reinterpret_cast<const float4*>(Gd + ((size_t)tokn << 8) + (u << 2));
    tk_next = tok_lds[s + 5];

    const f2* hq2 = reinterpret_cast<const f2*>(hls[cur] + (kq << 4));
    f2 ha = hq2[0], hb2 = hq2[1], hc = hq2[2], hd = hq2[3];
    f2 he = hq2[4], hf2 = hq2[5], hg = hq2[6], hh = hq2[7];
    // per-gate 16-elem dot via pk_fma: chains (x,y)=c01, (z,w)=c23,
    // per-component order identical to r9's b0..b3 chains (bit-exact).
#define GDOT(res, W0,W1,W2,W3,W4,W5,W6,W7) float res; { \
    f2 c01 = W0 * ha;  c01 = FMA2(W2, hc, c01); c01 = FMA2(W4, he, c01); c01 = FMA2(W6, hg, c01); \
    f2 c23 = W1 * hb2; c23 = FMA2(W3, hd, c23); c23 = FMA2(W5, hf2, c23); c23 = FMA2(W7, hh, c23); \
    res = (c01.x + c01.y) + (c23.x + c23.y); }
    GDOT(acc0, Wa0,Wa1,Wa2,Wa3,Wa4,Wa5,Wa6,Wa7)
    GDOT(acc1, Wb0,Wb1,Wb2,Wb3,Wb4,Wb5,Wb6,Wb7)
    GDOT(acc2, Wc0,Wc1,Wc2,Wc3,Wc4,Wc5,Wc6,Wc7)
    GDOT(acc3, Wd0,Wd1,Wd2,Wd3,Wd4,Wd5,Wd6,Wd7)
#undef GDOT
    // quad butterfly (DPP): every lane gets full 64-sum per gate
    float t0 = acc0 + qp_xor1(acc0); float f0 = t0 + qp_xor2(t0);
    float t1 = acc1 + qp_xor1(acc1); float f1 = t1 + qp_xor2(t1);
    float t2 = acc2 + qp_xor1(acc2); float f2v = t2 + qp_xor2(t2);
    float t3 = acc3 + qp_xor1(acc3); float f3 = t3 + qp_xor2(t3);
    float xi = f0 + gq0.x;
    float xf = f1 + gq0.y;
    float xg = f2v + gq0.z;
    float xo = f3 + gq0.w;
    float si = __builtin_amdgcn_rcpf(1.0f + __builtin_amdgcn_exp2f(xi * (-L2E)));
    float sf = __builtin_amdgcn_rcpf(1.0f + __builtin_amdgcn_exp2f(xf * (-L2E)));
    float tg = fmaf(2.0f, __builtin_amdgcn_rcpf(1.0f + __builtin_amdgcn_exp2f(xg * (-2.0f * L2E))), -1.0f);
    float so = __builtin_amdgcn_rcpf(1.0f + __builtin_amdgcn_exp2f(xo * (-L2E)));
    c = __fadd_rn(__fmul_rn(sf, c), __fmul_rn(si, tg));
    float tc = fmaf(2.0f, __builtin_amdgcn_rcpf(1.0f + __builtin_amdgcn_exp2f(c * (-2.0f * L2E))), -1.0f);
    float hn = __fmul_rn(so, tc);
    if (kq == 0) {
      hls[cur ^ 1][u] = hn;
      *hop = hn;
    }
    hop += hstep;
    // raw barrier: drain LDS only; global prefetch loads stay in flight
    asm volatile("s_waitcnt lgkmcnt(0)\n\ts_barrier" ::: "memory");
    cur ^= 1;
    gq0 = gq1; gq1 = gq2; gq2 = gq3; gq3 = gq4;
  }
}

// ============ K3: emissions = [hf|hb] @ W_out.T + b_out ============
// Round-10 rewrite: 1 position/thread, h in 32 pinned float4 (128 VGPR),
// W_out read UNIFORMLY (wave-invariant index -> s_load to SGPR, zero LDS).
__global__ __launch_bounds__(256)
__attribute__((amdgpu_waves_per_eu(2, 2)))
void k3_emit(
    const float* __restrict__ hbuf,
    const float* __restrict__ W_out,
    const float* __restrict__ b_out,
    float* __restrict__ emit)
{
  int pos = blockIdx.x * 256 + threadIdx.x;        // 0..131071
  const float* hfp = hbuf + (size_t)pos * 64;
  const float* hbp = hbuf + (size_t)B_ * T_ * 64 + (size_t)pos * 64;
#define LDH(name, base, q) float4 name = *reinterpret_cast<const float4*>((base) + 4 * (q)); PINF4(name)
  LDH(H0, hfp,0);  LDH(H1, hfp,1);  LDH(H2, hfp,2);  LDH(H3, hfp,3);
  LDH(H4, hfp,4);  LDH(H5, hfp,5);  LDH(H6, hfp,6);  LDH(H7, hfp,7);
  LDH(H8, hfp,8);  LDH(H9, hfp,9);  LDH(H10,hfp,10); LDH(H11,hfp,11);
  LDH(H12,hfp,12); LDH(H13,hfp,13); LDH(H14,hfp,14); LDH(H15,hfp,15);
  LDH(H16,hbp,0);  LDH(H17,hbp,1);  LDH(H18,hbp,2);  LDH(H19,hbp,3);
  LDH(H20,hbp,4);  LDH(H21,hbp,5);  LDH(H22,hbp,6);  LDH(H23,hbp,7);
  LDH(H24,hbp,8);  LDH(H25,hbp,9);  LDH(H26,hbp,10); LDH(H27,hbp,11);
  LDH(H28,hbp,12); LDH(H29,hbp,13); LDH(H30,hbp,14); LDH(H31,hbp,15);
#undef LDH
  float* ep = emit + (size_t)pos * K_;
#pragma unroll 1
  for (int k = 0; k < K_; ++k) {
    const float* wk = W_out + k * 128;   // uniform -> s_load
    float a0 = 0.f, a1 = 0.f, a2 = 0.f, a3 = 0.f;
#define K3F(Hq, q) { \
    a0 = fmaf(Hq.x, wk[4*(q)+0], a0); a1 = fmaf(Hq.y, wk[4*(q)+1], a1); \
    a2 = fmaf(Hq.z, wk[4*(q)+2], a2); a3 = fmaf(Hq.w, wk[4*(q)+3], a3); }
    K3F(H0,0)  K3F(H1,1)  K3F(H2,2)  K3F(H3,3)
    K3F(H4,4)  K3F(H5,5)  K3F(H6,6)  K3F(H7,7)
    K3F(H8,8)  K3F(H9,9)  K3F(H10,10)K3F(H11,11)
    K3F(H12,12)K3F(H13,13)K3F(H14,14)K3F(H15,15)
    K3F(H16,16)K3F(H17,17)K3F(H18,18)K3F(H19,19)
    K3F(H20,20)K3F(H21,21)K3F(H22,22)K3F(H23,23)
    K3F(H24,24)K3F(H25,25)K3F(H26,26)K3F(H27,27)
    K3F(H28,28)K3F(H29,29)K3F(H30,30)K3F(H31,31)
#undef K3F
    ep[k] = __fadd_rn((a0 + a1) + (a2 + a3), b_out[k]);
  }
}

// ============ K4: Viterbi forward. 1 wave per b; lane l = tag j ============
// Round-10 rewrite: scores broadcast via v_readlane -> SGPR (no ds_bpermute
// in the loop); each lane computes all 17 candidates + np first-index tree
// locally -> no cross-lane merge at all.
#define AMAX(vA, iA, vB, iB) { bool tk_ = (vB) > (vA); if (tk_) { vA = (vB); iA = (iB); } }

__global__ __launch_bounds__(64) void k4_viterbi(
    const float* __restrict__ emit,
    const float* __restrict__ trans,
    const float* __restrict__ start_trans,
    const float* __restrict__ end_trans,
    u8* __restrict__ bp,
    int* __restrict__ last,
    float* __restrict__ out)
{
  int b = blockIdx.x;
  int l = threadIdx.x;
  int jc = (l < K_) ? l : 0;
  // full trans column for tag j: tr_i = trans[i][j], named scalars
  float tr0  = trans[ 0 * K_ + jc], tr1  = trans[ 1 * K_ + jc];
  float tr2  = trans[ 2 * K_ + jc], tr3  = trans[ 3 * K_ + jc];
  float tr4  = trans[ 4 * K_ + jc], tr5  = trans[ 5 * K_ + jc];
  float tr6  = trans[ 6 * K_ + jc], tr7  = trans[ 7 * K_ + jc];
  float tr8  = trans[ 8 * K_ + jc], tr9  = trans[ 9 * K_ + jc];
  float tr10 = trans[10 * K_ + jc], tr11 = trans[11 * K_ + jc];
  float tr12 = trans[12 * K_ + jc], tr13 = trans[13 * K_ + jc];
  float tr14 = trans[14 * K_ + jc], tr15 = trans[15 * K_ + jc];
  float tr16 = trans[16 * K_ + jc];
  const float* eb = emit + (size_t)b * T_ * K_;
  float endt = end_trans[jc];
  float s = __fadd_rn(start_trans[jc], eb[jc]);
  u8* bpb = bp + (size_t)b * T_ * 32;
  // 8-deep emission ring (clamped indices, branch-free)
  float er0 = eb[1 * K_ + jc], er1 = eb[2 * K_ + jc];
  float er2 = eb[3 * K_ + jc], er3 = eb[4 * K_ + jc];
  float er4 = eb[5 * K_ + jc], er5 = eb[6 * K_ + jc];
  float er6 = eb[7 * K_ + jc], er7 = eb[8 * K_ + jc];

#pragma unroll 4
  for (int t = 1; t < T_; ++t) {
    float ej = er0;
    er0 = er1; er1 = er2; er2 = er3; er3 = er4;
    er4 = er5; er5 = er6; er6 = er7;
    int tn = (t + 8 < T_) ? (t + 8) : (T_ - 1);
    er7 = eb[(size_t)tn * K_ + jc];
    // broadcast all 17 scores to SGPRs (lane i holds score[i])
    float sg0  = rdl(s, 0),  sg1  = rdl(s, 1),  sg2  = rdl(s, 2);
    float sg3  = rdl(s, 3),  sg4  = rdl(s, 4),  sg5  = rdl(s, 5);
    float sg6  = rdl(s, 6),  sg7  = rdl(s, 7),  sg8  = rdl(s, 8);
    float sg9  = rdl(s, 9),  sg10 = rdl(s, 10), sg11 = rdl(s, 11);
    float sg12 = rdl(s, 12), sg13 = rdl(s, 13), sg14 = rdl(s, 14);
    float sg15 = rdl(s, 15), sg16 = rdl(s, 16);
    // np rounding order: cand_i = (score_i + trans_ij) + emit_j
    float c0  = __fadd_rn(__fadd_rn(sg0,  tr0),  ej);
    float c1  = __fadd_rn(__fadd_rn(sg1,  tr1),  ej);
    float c2  = __fadd_rn(__fadd_rn(sg2,  tr2),  ej);
    float c3  = __fadd_rn(__fadd_rn(sg3,  tr3),  ej);
    float c4  = __fadd_rn(__fadd_rn(sg4,  tr4),  ej);
    float c5  = __fadd_rn(__fadd_rn(sg5,  tr5),  ej);
    float c6  = __fadd_rn(__fadd_rn(sg6,  tr6),  ej);
    float c7  = __fadd_rn(__fadd_rn(sg7,  tr7),  ej);
    float c8  = __fadd_rn(__fadd_rn(sg8,  tr8),  ej);
    float c9  = __fadd_rn(__fadd_rn(sg9,  tr9),  ej);
    float c10 = __fadd_rn(__fadd_rn(sg10, tr10), ej);
    float c11 = __fadd_rn(__fadd_rn(sg11, tr11), ej);
    float c12 = __fadd_rn(__fadd_rn(sg12, tr12), ej);
    float c13 = __fadd_rn(__fadd_rn(sg13, tr13), ej);
    float c14 = __fadd_rn(__fadd_rn(sg14, tr14), ej);
    float c15 = __fadd_rn(__fadd_rn(sg15, tr15), ej);
    float c16 = __fadd_rn(__fadd_rn(sg16, tr16), ej);
    // first-index argmax tree (strict >, left-priority == np tie rule)
    float v0 = c0;  int x0 = 0;  AMAX(v0, x0, c1, 1);
    float v1 = c2;  int x1 = 2;  AMAX(v1, x1, c3, 3);
    float v2 = c4;  int x2 = 4;  AMAX(v2, x2, c5, 5);
    float v3 = c6;  int x3 = 6;  AMAX(v3, x3, c7, 7);
    float v4 = c8;  int x4 = 8;  AMAX(v4, x4, c9, 9);
    float v5 = c10; int x5 = 10; AMAX(v5, x5, c11, 11);
    float v6 = c12; int x6 = 12; AMAX(v6, x6, c13, 13);
    float v7 = c14; int x7 = 14; AMAX(v7, x7, c15, 15);
    AMAX(v0, x0, v1, x1); AMAX(v2, x2, v3, x3);
    AMAX(v4, x4, v5, x5); AMAX(v6, x6, v7, x7);
    AMAX(v0, x0, v2, x2); AMAX(v4, x4, v6, x6);
    AMAX(v0, x0, v4, x4);
    AMAX(v0, x0, c16, 16);
    s = v0;
    if (l < K_) bpb[(size_t)(t - 1) * 32 + l] = (u8)x0;
  }
  float fin = __fadd_rn(s, endt);
  // final argmax over tags (uniform via readlane, same first-index tree)
  float g0  = rdl(fin, 0),  g1  = rdl(fin, 1),  g2  = rdl(fin, 2);
  float g3  = rdl(fin, 3),  g4  = rdl(fin, 4),  g5  = rdl(fin, 5);
  float g6  = rdl(fin, 6),  g7  = rdl(fin, 7),  g8  = rdl(fin, 8);
  float g9  = rdl(fin, 9),  g10 = rdl(fin, 10), g11 = rdl(fin, 11);
  float g12 = rdl(fin, 12), g13 = rdl(fin, 13), g14 = rdl(fin, 14);
  float g15 = rdl(fin, 15), g16 = rdl(fin, 16);
  float w0 = g0;  int y0 = 0;  AMAX(w0, y0, g1, 1);
  float w1 = g2;  int y1 = 2;  AMAX(w1, y1, g3, 3);
  float w2 = g4;  int y2 = 4;  AMAX(w2, y2, g5, 5);
  float w3 = g6;  int y3 = 6;  AMAX(w3, y3, g7, 7);
  float w4 = g8;  int y4 = 8;  AMAX(w4, y4, g9, 9);
  float w5 = g10; int y5 = 10; AMAX(w5, y5, g11, 11);
  float w6 = g12; int y6 = 12; AMAX(w6, y6, g13, 13);
  float w7 = g14; int y7 = 14; AMAX(w7, y7, g15, 15);
  AMAX(w0, y0, w1, y1); AMAX(w2, y2, w3, y3);
  AMAX(w4, y4, w5, y5); AMAX(w6, y6, w7, y7);
  AMAX(w0, y0, w2, y2); AMAX(w4, y4, w6, y6);
  AMAX(w0, y0, w4, y4);
  AMAX(w0, y0, g16, 16);
  if (l == 0) {
    out[b] = w0;
    last[b] = y0;
    out[256 + (size_t)b * T_ + (T_ - 1)] = (float)y0;
  }
}

// ============ K5: backtrace — 8-deep double-buffered prefetch ============
__global__ __launch_bounds__(64) void k5_backtrace(
    const u8* __restrict__ bp,
    const int* __restrict__ last,
    float* __restrict__ out)
{
  int b = blockIdx.x * 64 + threadIdx.x;
  const u8* base = bp + (size_t)b * T_ * 32;
  int tag = last[b];
  float* ob = out + 256 + (size_t)b * T_;
  uint4 A0[8], A1[8];
  u32 B0[8], B1[8];
#pragma unroll
  for (int q = 0; q < 8; ++q) {
    const u8* p = base + (size_t)(510 - q) * 32;
    A0[q] = *reinterpret_cast<const uint4*>(p);
    B0[q] = *reinterpret_cast<const u32*>(p + 16);
  }
  int t0 = 510;
  for (int pair = 0; pair < 32; ++pair) {
#pragma unroll
    for (int q = 0; q < 8; ++q) {
      int tn = t0 - 8 - q;
      if (tn >= 0) {
        const u8* p = base + (size_t)tn * 32;
        A1[q] = *reinterpret_cast<const uint4*>(p);
        B1[q] = *reinterpret_cast<const u32*>(p + 16);
      }
    }
#pragma unroll
    for (int q = 0; q < 8; ++q) {
      int t = t0 - q;
      if (t >= 0) {
        uint4 Av = A0[q]; u32 Bw = B0[q];
        u32 dw = (tag < 8) ? ((tag < 4) ? Av.x : Av.y) : ((tag < 12) ? Av.z : Av.w);
        dw = (tag < 16) ? dw : Bw;
        tag = (int)((dw >> ((tag & 3) * 8)) & 0xffu);
        ob[t] = (float)tag;
      }
    }
#pragma unroll
    for (int q = 0; q < 8; ++q) {
      int tn = t0 - 16 - q;
      if (tn >= 0) {
        const u8* p = base + (size_t)tn * 32;
        A0[q] = *reinterpret_cast<const uint4*>(p);
        B0[q] = *reinterpret_cast<const u32*>(p + 16);
      }
    }
#pragma unroll
    for (int q = 0; q < 8; ++q) {
      int t = t0 - 8 - q;
      if (t >= 0) {
        uint4 Av = A1[q]; u32 Bw = B1[q];
        u32 dw = (tag < 8) ? ((tag < 4) ? Av.x : Av.y) : ((tag < 12) ? Av.z : Av.w);
        dw = (tag < 16) ? dw : Bw;
        tag = (int)((dw >> ((tag & 3) * 8)) & 0xffu);
        ob[t] = (float)tag;
      }
    }
    t0 -= 16;
  }
}

extern "C" void kernel_launch(void* const* d_in, const int* in_sizes, int n_in,
                              void* d_out, int out_size, void* d_ws, size_t ws_size,
                              hipStream_t stream) {
  const int*   data  = (const int*)d_in[0];
  const float* emb   = (const float*)d_in[2];
  const float* Wih_f = (const float*)d_in[3];
  const float* Whh_f = (const float*)d_in[4];
  const float* bih_f = (const float*)d_in[5];
  const float* bhh_f = (const float*)d_in[6];
  const float* Wih_b = (const float*)d_in[7];
  const float* Whh_b = (const float*)d_in[8];
  const float* bih_b = (const float*)d_in[9];
  const float* bhh_b = (const float*)d_in[10];
  const float* W_out = (const float*)d_in[11];
  const float* b_out = (const float*)d_in[12];
  const float* trans = (const float*)d_in[13];
  const float* start_trans = (const float*)d_in[14];
  const float* end_trans   = (const float*)d_in[15];

  char* ws = (char*)d_ws;
  float* G    = (float*)(ws + WS_G);
  float* hbuf = (float*)(ws + WS_H);
  float* emit = (float*)(ws + WS_EMIT);
  u8*    bp   = (u8*)(ws + WS_BP);
  int*   lastp = (int*)(ws + WS_LAST);
  float* out = (float*)d_out;

  k1_build_G<<<dim3(250, 2), 256, 0, stream>>>(emb, Wih_f, bih_f, bhh_f,
                                               Wih_b, bih_b, bhh_b, G);
  k2_lstm<<<512, 256, 0, stream>>>(data, G, Whh_f, Whh_b, hbuf);
  k3_emit<<<512, 256, 0, stream>>>(hbuf, W_out, b_out, emit);
  k4_viterbi<<<256, 64, 0, stream>>>(emit, trans, start_trans, end_trans,
                                     bp, lastp, out);
  k5_backtrace<<<4, 64, 0, stream>>>(bp, lastp, out);
}